// Round 2
// baseline (370.067 us; speedup 1.0000x reference)
//
#include <hip/hip_runtime.h>

// FeatNeighbourCorr: feats [B=8, C=128, H=256, W=256] fp32 -> out [B,8,H,W] fp32.
// out[b,k,h,w] = dot_k(h,w) * rsqrt(ssq(h,w)) * rsqrt(ssq(neighbor_k))
//
// V2: multi-row block + LDS-staged channel pipeline.
//  - Block = 4 waves (256 thr). Wave w computes output row h0+w (h0 = 4*blockIdx.x).
//  - Per channel, block stages rows h0-1 .. h0+4 (6 rows = 6 KB, contiguous in
//    memory) into LDS via global_load_lds width=16 (wave-uniform LDS base +
//    lane*16; per-lane global addr). Traffic = 1.5x input (~415 MB) vs 3x before.
//  - Channel pipeline P=10 buffers deep (60 KB LDS), counted-vmcnt waits
//    (never vmcnt(0) in steady state), raw s_barrier. ~108 KB/CU in flight.
//  - Wave w reads slots w, w+1, w+2 of the staged buffer (t/m/b rows) as
//    float4 + 3 shfl_down; 44-acc compute and boundary-exchange epilogue are
//    IDENTICAL to the verified V1 kernel. No cross-wave reduction needed
//    (each wave accumulates all 128 channels of its own row).
//
// Staging assignment: wave w stages slot w every channel; waves 0,1 also
// stage slots 4,5. So c_w = 2 stage-ops/channel for waves 0,1 and 1 for
// waves 2,3 -> per-wave steady vmcnt = c_w * (P-1) = 18 / 9.
// Tail (last P-1 channels): vmcnt(0) (everything already issued).

#define BB 8
#define CC 128
#define HH 256
#define WW 256
#define RB 4            // output rows per block
#define NSLOT 6         // staged rows per channel = RB+2
#define PD 10           // channel prefetch depth (buffers); LDS = PD*6KB = 60KB

#define DD(k, j) acc[12 + (k)*4 + (j)]

__global__ __launch_bounds__(256) void featcorr_kernel(
    const float* __restrict__ feats, float* __restrict__ out) {
  const int lane = threadIdx.x;  // 0..63
  const int wy = threadIdx.y;    // 0..3; wave w computes row h0+w
  const int rb = blockIdx.x;     // 0..63
  const int b = blockIdx.y;
  const int h0 = rb * RB;
  const int h = h0 + wy;

  const size_t HW = (size_t)HH * WW;
  const int col0 = lane * 4;

  __shared__ float lds[PD][NSLOT][WW];  // 60 KB

  // ---- staging source pointers (channels visited in increasing order) ----
  // slot r <-> absolute row h0-1+r; reflect-pad at image edges (+-1 only).
  const int hh1 = h0 - 1 + wy;
  const int sr1 = (hh1 < 0) ? 1 : (hh1 > HH - 1 ? HH - 2 : hh1);
  const float* p1 = feats + (size_t)b * CC * HW + (size_t)sr1 * WW + col0;
  const float* p2 = nullptr;
  if (wy < 2) {
    const int hh2 = h0 - 1 + (4 + wy);
    const int sr2 = (hh2 < 0) ? 1 : (hh2 > HH - 1 ? HH - 2 : hh2);
    p2 = feats + (size_t)b * CC * HW + (size_t)sr2 * WW + col0;
  }

  auto stage = [&](int buf) {
    __builtin_amdgcn_global_load_lds(
        (const __attribute__((address_space(1))) void*)p1,
        (__attribute__((address_space(3))) void*)&lds[buf][wy][0], 16, 0, 0);
    p1 += HW;
    if (wy < 2) {
      __builtin_amdgcn_global_load_lds(
          (const __attribute__((address_space(1))) void*)p2,
          (__attribute__((address_space(3))) void*)&lds[buf][4 + wy][0], 16, 0, 0);
      p2 += HW;
    }
  };

  float acc[44];
#pragma unroll
  for (int a = 0; a < 44; ++a) acc[a] = 0.f;

  auto compute = [&](int buf) {
    const float4 t = *(const float4*)&lds[buf][wy][col0];
    const float4 m = *(const float4*)&lds[buf][wy + 1][col0];
    const float4 bt = *(const float4*)&lds[buf][wy + 2][col0];
    const float rT = __shfl_down(t.x, 1);
    const float rM = __shfl_down(m.x, 1);
    const float rB = __shfl_down(bt.x, 1);
    // squared sums (rows h-1 / h / h+1)
    acc[0] += t.x * t.x;  acc[1] += t.y * t.y;  acc[2] += t.z * t.z;  acc[3] += t.w * t.w;
    acc[4] += m.x * m.x;  acc[5] += m.y * m.y;  acc[6] += m.z * m.z;  acc[7] += m.w * m.w;
    acc[8] += bt.x * bt.x; acc[9] += bt.y * bt.y; acc[10] += bt.z * bt.z; acc[11] += bt.w * bt.w;
    // k0 (h-1, w)
    DD(0, 0) += m.x * t.x; DD(0, 1) += m.y * t.y; DD(0, 2) += m.z * t.z; DD(0, 3) += m.w * t.w;
    // k4 (h+1, w)
    DD(4, 0) += m.x * bt.x; DD(4, 1) += m.y * bt.y; DD(4, 2) += m.z * bt.z; DD(4, 3) += m.w * bt.w;
    // k1 (h-1, w-1): j=1..3 local; slot (1,0) = boundary term for right lane
    DD(1, 1) += m.y * t.x; DD(1, 2) += m.z * t.y; DD(1, 3) += m.w * t.z;
    DD(1, 0) += rM * t.w;
    // k2 (h, w-1): boundary term rM*m.w merged into DD(6,3)
    DD(2, 1) += m.y * m.x; DD(2, 2) += m.z * m.y; DD(2, 3) += m.w * m.z;
    // k3 (h+1, w-1)
    DD(3, 1) += m.y * bt.x; DD(3, 2) += m.z * bt.y; DD(3, 3) += m.w * bt.z;
    DD(3, 0) += rM * bt.w;
    // k5 (h+1, w+1)
    DD(5, 0) += m.x * bt.y; DD(5, 1) += m.y * bt.z; DD(5, 2) += m.z * bt.w; DD(5, 3) += m.w * rB;
    // k6 (h, w+1); DD(6,3) doubles as the k2 boundary term for lane+1
    DD(6, 0) += m.x * m.y; DD(6, 1) += m.y * m.z; DD(6, 2) += m.z * m.w; DD(6, 3) += m.w * rM;
    // k7 (h-1, w+1)
    DD(7, 0) += m.x * t.y; DD(7, 1) += m.y * t.z; DD(7, 2) += m.z * t.w; DD(7, 3) += m.w * rT;
  };

  // ---- prologue: fill all PD buffers (channels 0..PD-1) ----
#pragma unroll
  for (int c = 0; c < PD; ++c) stage(c);

  // ---- main channel loop: 2 barriers/channel, counted vmcnt ----
  int buf = 0;
  for (int ch = 0; ch < CC; ++ch) {
    if (ch < CC - (PD - 1)) {
      // wait for own stage-ops of channel ch; keep (PD-1) channels in flight
      if (wy < 2) {
        asm volatile("s_waitcnt vmcnt(18)" ::: "memory");
      } else {
        asm volatile("s_waitcnt vmcnt(9)" ::: "memory");
      }
    } else {
      asm volatile("s_waitcnt vmcnt(0)" ::: "memory");
    }
    asm volatile("s_barrier" ::: "memory");  // stage(ch) visible to all waves
    compute(buf);
    // ds_read data must be returned before buffer is overwritten
    asm volatile("s_waitcnt lgkmcnt(0)" ::: "memory");
    asm volatile("s_barrier" ::: "memory");  // all waves done reading buf
    if (ch + PD < CC) stage(buf);            // (ch+PD) % PD == buf
    buf = (buf + 1 == PD) ? 0 : buf + 1;
  }

  // ---- epilogue (per wave; identical to verified V1) ----
  // deliver left-lane boundary dots; reflect edges via symmetry
  const float g1 = __shfl_up(DD(1, 0), 1);
  const float g2 = __shfl_up(DD(6, 3), 1);  // merged k2 boundary
  const float g3 = __shfl_up(DD(3, 0), 1);
  DD(1, 0) = (lane == 0) ? DD(7, 0) : g1;
  DD(2, 0) = (lane == 0) ? DD(6, 0) : g2;
  DD(3, 0) = (lane == 0) ? DD(5, 0) : g3;
  if (lane == 63) {
    DD(5, 3) = DD(3, 3);
    DD(6, 3) = DD(2, 3);
    DD(7, 3) = DD(1, 3);
  }

  float it[4], im[4], ib[4];
#pragma unroll
  for (int j = 0; j < 4; ++j) {
    it[j] = rsqrtf(acc[j]);
    im[j] = rsqrtf(acc[4 + j]);
    ib[j] = rsqrtf(acc[8 + j]);
  }
  // neighbor inverse norms over cols [col0-1 .. col0+4]
  float IT[6], IM[6], IB[6];
  IT[1] = it[0]; IT[2] = it[1]; IT[3] = it[2]; IT[4] = it[3];
  IM[1] = im[0]; IM[2] = im[1]; IM[3] = im[2]; IM[4] = im[3];
  IB[1] = ib[0]; IB[2] = ib[1]; IB[3] = ib[2]; IB[4] = ib[3];
  const float tl = __shfl_up(it[3], 1), ml = __shfl_up(im[3], 1), bl = __shfl_up(ib[3], 1);
  const float tr = __shfl_down(it[0], 1), mr = __shfl_down(im[0], 1), br = __shfl_down(ib[0], 1);
  IT[0] = (lane == 0) ? it[1] : tl;
  IM[0] = (lane == 0) ? im[1] : ml;
  IB[0] = (lane == 0) ? ib[1] : bl;
  IT[5] = (lane == 63) ? it[2] : tr;
  IM[5] = (lane == 63) ? im[2] : mr;
  IB[5] = (lane == 63) ? ib[2] : br;

  float* obase = out + ((size_t)b * 8) * HW + (size_t)h * WW + col0;
#pragma unroll
  for (int k = 0; k < 8; ++k) {
    float v[4];
#pragma unroll
    for (int j = 0; j < 4; ++j) {
      float in;
      switch (k) {
        case 0: in = it[j];     break;  // (h-1, w)
        case 1: in = IT[j];     break;  // (h-1, w-1)
        case 2: in = IM[j];     break;  // (h,   w-1)
        case 3: in = IB[j];     break;  // (h+1, w-1)
        case 4: in = ib[j];     break;  // (h+1, w)
        case 5: in = IB[j + 2]; break;  // (h+1, w+1)
        case 6: in = IM[j + 2]; break;  // (h,   w+1)
        default: in = IT[j + 2]; break; // (h-1, w+1)
      }
      v[j] = DD(k, j) * im[j] * in;
    }
    float4 o;
    o.x = v[0]; o.y = v[1]; o.z = v[2]; o.w = v[3];
    *(float4*)(obase + (size_t)k * HW) = o;
  }
}

extern "C" void kernel_launch(void* const* d_in, const int* in_sizes, int n_in,
                              void* d_out, int out_size, void* d_ws, size_t ws_size,
                              hipStream_t stream) {
  const float* feats = (const float*)d_in[0];
  float* out = (float*)d_out;
  dim3 block(64, RB, 1);
  dim3 grid(HH / RB, BB, 1);
  featcorr_kernel<<<grid, block, 0, stream>>>(feats, out);
}

// Round 3
// 357.622 us; speedup vs baseline: 1.0348x; 1.0348x over previous
//
#include <hip/hip_runtime.h>

// FeatNeighbourCorr: feats [B=8, C=128, H=256, W=256] fp32 -> out [B,8,H,W] fp32.
// out[b,k,h,w] = dot_k(h,w) * rsqrt(ssq(h,w)) * rsqrt(ssq(neighbor_k))
//
// V3: 8-row block, single-barrier channel pipeline.
//  - Block = 8 waves (512 thr). Wave w computes output row h0+w (h0 = 8*blockIdx.x).
//  - Per channel, block stages rows h0-1 .. h0+8 (10 rows = 10 KB contiguous)
//    via global_load_lds width=16. Traffic = 1.25x input (~353 MB total).
//  - NBUF=6 channel buffers (60 KB LDS), PD=5 channels in flight.
//    ONE barrier per channel: stage(ch+5) at iteration ch targets buffer
//    (ch+5)%6 == buffer read at iteration ch-1; all waves' reads of it are
//    ordered before barrier(ch) (asm memory clobber), so the overwrite is safe.
//  - Counted per-wave vmcnt (waves 0,1 stage 2 rows/ch -> vmcnt(8); waves 2..7
//    stage 1 row/ch -> vmcnt(4)); vmcnt(0) only once, entering the 5-channel tail.
//  - 44-acc compute + boundary-exchange epilogue identical to verified V1/V2.

#define BB 8
#define CC 128
#define HH 256
#define WW 256
#define RB 8            // output rows per block
#define NSLOT (RB + 2)  // 10 staged rows per channel
#define NBUF 6          // channel buffers; LDS = NBUF*10KB = 60KB
#define PD 5            // channels in flight (= NBUF-1)

#define DD(k, j) acc[12 + (k)*4 + (j)]

__global__ __launch_bounds__(512) void featcorr_kernel(
    const float* __restrict__ feats, float* __restrict__ out) {
  const int lane = threadIdx.x;  // 0..63
  const int wy = threadIdx.y;    // 0..7; wave w computes row h0+w
  const int b = blockIdx.y;
  const int h0 = blockIdx.x * RB;
  const int h = h0 + wy;

  const size_t HW = (size_t)HH * WW;
  const int col0 = lane * 4;

  __shared__ float lds[NBUF][NSLOT][WW];  // 60 KB
  __shared__ float lds_pad[4];            // absorbs lane63 col+4 overread of last slot
  (void)lds_pad;

  // ---- staging source pointers ----
  // slot r <-> absolute row h0-1+r; reflect at image edges (+-1 only).
  const int hh1 = h0 - 1 + wy;
  const int sr1 = (hh1 < 0) ? 1 : (hh1 > HH - 1 ? HH - 2 : hh1);
  const float* p1 = feats + (size_t)b * CC * HW + (size_t)sr1 * WW + col0;
  const float* p2 = nullptr;
  if (wy < 2) {
    const int hh2 = h0 - 1 + (RB + wy);
    const int sr2 = (hh2 < 0) ? 1 : (hh2 > HH - 1 ? HH - 2 : hh2);
    p2 = feats + (size_t)b * CC * HW + (size_t)sr2 * WW + col0;
  }

  auto stage = [&](int buf) {
    __builtin_amdgcn_global_load_lds(
        (const __attribute__((address_space(1))) void*)p1,
        (__attribute__((address_space(3))) void*)&lds[buf][wy][0], 16, 0, 0);
    p1 += HW;
    if (wy < 2) {
      __builtin_amdgcn_global_load_lds(
          (const __attribute__((address_space(1))) void*)p2,
          (__attribute__((address_space(3))) void*)&lds[buf][RB + wy][0], 16, 0, 0);
      p2 += HW;
    }
  };

  float acc[44];
#pragma unroll
  for (int a = 0; a < 44; ++a) acc[a] = 0.f;

  auto compute = [&](int buf) {
    const float4 t = *(const float4*)&lds[buf][wy][col0];
    const float4 m = *(const float4*)&lds[buf][wy + 1][col0];
    const float4 bt = *(const float4*)&lds[buf][wy + 2][col0];
    const float rT = __shfl_down(t.x, 1);
    const float rM = __shfl_down(m.x, 1);
    const float rB = __shfl_down(bt.x, 1);
    // squared sums (rows h-1 / h / h+1)
    acc[0] += t.x * t.x;  acc[1] += t.y * t.y;  acc[2] += t.z * t.z;  acc[3] += t.w * t.w;
    acc[4] += m.x * m.x;  acc[5] += m.y * m.y;  acc[6] += m.z * m.z;  acc[7] += m.w * m.w;
    acc[8] += bt.x * bt.x; acc[9] += bt.y * bt.y; acc[10] += bt.z * bt.z; acc[11] += bt.w * bt.w;
    // k0 (h-1, w)
    DD(0, 0) += m.x * t.x; DD(0, 1) += m.y * t.y; DD(0, 2) += m.z * t.z; DD(0, 3) += m.w * t.w;
    // k4 (h+1, w)
    DD(4, 0) += m.x * bt.x; DD(4, 1) += m.y * bt.y; DD(4, 2) += m.z * bt.z; DD(4, 3) += m.w * bt.w;
    // k1 (h-1, w-1): j=1..3 local; slot (1,0) = boundary term for right lane
    DD(1, 1) += m.y * t.x; DD(1, 2) += m.z * t.y; DD(1, 3) += m.w * t.z;
    DD(1, 0) += rM * t.w;
    // k2 (h, w-1): boundary term rM*m.w merged into DD(6,3)
    DD(2, 1) += m.y * m.x; DD(2, 2) += m.z * m.y; DD(2, 3) += m.w * m.z;
    // k3 (h+1, w-1)
    DD(3, 1) += m.y * bt.x; DD(3, 2) += m.z * bt.y; DD(3, 3) += m.w * bt.z;
    DD(3, 0) += rM * bt.w;
    // k5 (h+1, w+1)
    DD(5, 0) += m.x * bt.y; DD(5, 1) += m.y * bt.z; DD(5, 2) += m.z * bt.w; DD(5, 3) += m.w * rB;
    // k6 (h, w+1); DD(6,3) doubles as the k2 boundary term for lane+1
    DD(6, 0) += m.x * m.y; DD(6, 1) += m.y * m.z; DD(6, 2) += m.z * m.w; DD(6, 3) += m.w * rM;
    // k7 (h-1, w+1)
    DD(7, 0) += m.x * t.y; DD(7, 1) += m.y * t.z; DD(7, 2) += m.z * t.w; DD(7, 3) += m.w * rT;
  };

  // ---- prologue: stage channels 0..PD-1 into buffers 0..PD-1 ----
#pragma unroll
  for (int c = 0; c < PD; ++c) stage(c);

  // ---- main loop: ONE barrier per channel, counted vmcnt ----
  int rbuf = 0;        // buffer holding channel ch
  int sbuf = PD;       // buffer for channel ch+PD
  for (int ch = 0; ch < CC - PD; ++ch) {  // ch = 0..122
    // own stage-ops for channel ch retired; keep PD-1 channels in flight
    if (wy < 2) {
      asm volatile("s_waitcnt vmcnt(8)" ::: "memory");
    } else {
      asm volatile("s_waitcnt vmcnt(4)" ::: "memory");
    }
    asm volatile("s_barrier" ::: "memory");  // channel ch visible; prev reads done
    compute(rbuf);
    stage(sbuf);  // channel ch+PD -> buffer last read at iteration ch-1
    rbuf = (rbuf + 1 == NBUF) ? 0 : rbuf + 1;
    sbuf = (sbuf + 1 == NBUF) ? 0 : sbuf + 1;
  }
  // ---- tail: channels 123..127 all staged; one drain + barrier, then free-run
  asm volatile("s_waitcnt vmcnt(0)" ::: "memory");
  asm volatile("s_barrier" ::: "memory");
#pragma unroll
  for (int k = 0; k < PD; ++k) {
    compute(rbuf);
    rbuf = (rbuf + 1 == NBUF) ? 0 : rbuf + 1;
  }

  // ---- epilogue (per wave; identical to verified V1/V2) ----
  const float g1 = __shfl_up(DD(1, 0), 1);
  const float g2 = __shfl_up(DD(6, 3), 1);  // merged k2 boundary
  const float g3 = __shfl_up(DD(3, 0), 1);
  DD(1, 0) = (lane == 0) ? DD(7, 0) : g1;
  DD(2, 0) = (lane == 0) ? DD(6, 0) : g2;
  DD(3, 0) = (lane == 0) ? DD(5, 0) : g3;
  if (lane == 63) {
    DD(5, 3) = DD(3, 3);
    DD(6, 3) = DD(2, 3);
    DD(7, 3) = DD(1, 3);
  }

  float it[4], im[4], ib[4];
#pragma unroll
  for (int j = 0; j < 4; ++j) {
    it[j] = rsqrtf(acc[j]);
    im[j] = rsqrtf(acc[4 + j]);
    ib[j] = rsqrtf(acc[8 + j]);
  }
  // neighbor inverse norms over cols [col0-1 .. col0+4]
  float IT[6], IM[6], IB[6];
  IT[1] = it[0]; IT[2] = it[1]; IT[3] = it[2]; IT[4] = it[3];
  IM[1] = im[0]; IM[2] = im[1]; IM[3] = im[2]; IM[4] = im[3];
  IB[1] = ib[0]; IB[2] = ib[1]; IB[3] = ib[2]; IB[4] = ib[3];
  const float tl = __shfl_up(it[3], 1), ml = __shfl_up(im[3], 1), bl = __shfl_up(ib[3], 1);
  const float tr = __shfl_down(it[0], 1), mr = __shfl_down(im[0], 1), br = __shfl_down(ib[0], 1);
  IT[0] = (lane == 0) ? it[1] : tl;
  IM[0] = (lane == 0) ? im[1] : ml;
  IB[0] = (lane == 0) ? ib[1] : bl;
  IT[5] = (lane == 63) ? it[2] : tr;
  IM[5] = (lane == 63) ? im[2] : mr;
  IB[5] = (lane == 63) ? ib[2] : br;

  float* obase = out + ((size_t)b * 8) * HW + (size_t)h * WW + col0;
#pragma unroll
  for (int k = 0; k < 8; ++k) {
    float v[4];
#pragma unroll
    for (int j = 0; j < 4; ++j) {
      float in;
      switch (k) {
        case 0: in = it[j];     break;  // (h-1, w)
        case 1: in = IT[j];     break;  // (h-1, w-1)
        case 2: in = IM[j];     break;  // (h,   w-1)
        case 3: in = IB[j];     break;  // (h+1, w-1)
        case 4: in = ib[j];     break;  // (h+1, w)
        case 5: in = IB[j + 2]; break;  // (h+1, w+1)
        case 6: in = IM[j + 2]; break;  // (h,   w+1)
        default: in = IT[j + 2]; break; // (h-1, w+1)
      }
      v[j] = DD(k, j) * im[j] * in;
    }
    float4 o;
    o.x = v[0]; o.y = v[1]; o.z = v[2]; o.w = v[3];
    *(float4*)(obase + (size_t)k * HW) = o;
  }
}

extern "C" void kernel_launch(void* const* d_in, const int* in_sizes, int n_in,
                              void* d_out, int out_size, void* d_ws, size_t ws_size,
                              hipStream_t stream) {
  const float* feats = (const float*)d_in[0];
  float* out = (float*)d_out;
  dim3 block(64, RB, 1);
  dim3 grid(HH / RB, BB, 1);
  featcorr_kernel<<<grid, block, 0, stream>>>(feats, out);
}